// Round 21
// baseline (98.493 us; speedup 1.0000x reference)
//
#include <hip/hip_runtime.h>
#include <hip/hip_bf16.h>

#define BATCH 8
#define CIN 256
#define CD 128
#define NPIX 4096  // 64*64
#define XLD 264    // staged-X row stride (shorts): 528B == 4 banks mod 32

typedef __attribute__((ext_vector_type(2))) float f32x2;
typedef __attribute__((ext_vector_type(4))) float f32x4;
typedef __attribute__((ext_vector_type(16))) float f32x16;
typedef __attribute__((ext_vector_type(8))) short s16x8;
typedef __attribute__((ext_vector_type(4))) short s16x4;
typedef __attribute__((ext_vector_type(2))) unsigned u32x2;
typedef __attribute__((ext_vector_type(2))) long l64x2;
typedef __attribute__((ext_vector_type(8))) int i32x8;

__device__ __forceinline__ short f2bf(float f) {
  union { float f; unsigned u; } v; v.f = f;
  unsigned r = v.u + 0x7fffu + ((v.u >> 16) & 1u);
  return (short)(r >> 16);
}
__device__ __forceinline__ float bf2f(short s) {
  union { unsigned u; float f; } v; v.u = ((unsigned)(unsigned short)s) << 16;
  return v.f;
}
__device__ __forceinline__ float asf(unsigned u) {
  union { unsigned u; float f; } v; v.u = u; return v.f;
}
__device__ __forceinline__ unsigned asu(float f) {
  union { float f; unsigned u; } v; v.f = f; return v.u;
}
// v_cvt_pk_bf16_f32 (T12)
__device__ __forceinline__ unsigned pkbf(float a, float b) {
  unsigned r;
  asm("v_cvt_pk_bf16_f32 %0, %1, %2" : "=v"(r) : "v"(a), "v"(b));
  return r;
}
// scalar f32 -> fp8 e4m3 (OCP), via packed cvt
__device__ __forceinline__ char f2fp8(float v) {
  return (char)((unsigned)__builtin_amdgcn_cvt_pk_fp8_f32(v, v, 0, false) & 0xffu);
}

#define MFMA(a, b, c) __builtin_amdgcn_mfma_f32_16x16x32_bf16((a), (b), (c), 0, 0, 0)
#define MFMA32(a, b, c) __builtin_amdgcn_mfma_f32_32x32x16_bf16((a), (b), (c), 0, 0, 0)
// MX-scaled fp8 K=64, scales = E8M0 127 -> x1.0 exact (2x the K=16 fp8 rate)
#define MFMAX(a, b, c) \
  __builtin_amdgcn_mfma_scale_f32_32x32x64_f8f6f4((a), (b), (c), 0, 0, 0, 127, 0, 127)

// async global->LDS, 16B per lane (char-ptr version)
__device__ __forceinline__ void g2l16b(const char* g, char* l) {
  __builtin_amdgcn_global_load_lds(
      (const __attribute__((address_space(1))) void*)g,
      (__attribute__((address_space(3))) void*)l, 16, 0, 0);
}

// b128 LDS read, viewed as 2x i64
__device__ __forceinline__ l64x2 ld128(const char* p) {
  union { s16x8 v; l64x2 l; } u;
  u.v = *(const s16x8*)p;
  return u.l;
}
// build the 8-VGPR (32B) MX operand from two b128s / four i64s
__device__ __forceinline__ i32x8 mk8(l64x2 a, l64x2 b) {
  union { long l[4]; i32x8 v; } u;
  u.l[0] = a.x; u.l[1] = a.y; u.l[2] = b.x; u.l[3] = b.y;
  return u.v;
}
__device__ __forceinline__ i32x8 mk8l(long a, long b, long c, long d) {
  union { long l[4]; i32x8 v; } u;
  u.l[0] = a; u.l[1] = b; u.l[2] = c; u.l[3] = d;
  return u.v;
}

// ---------------------------------------------------------------- kernel 0
__global__ void k_wconv(const float* __restrict__ Wq, const float* __restrict__ Wk,
                        const float* __restrict__ Wv, const float* __restrict__ Wt,
                        const float* __restrict__ Wf, short* __restrict__ out) {
  int idx = blockIdx.x * 256 + threadIdx.x;  // 0..163839
  int region = idx >> 15;
  const float* src = (region == 0) ? Wq : (region == 1) ? Wk : (region == 2) ? Wv
                     : (region == 3) ? Wt : Wf;
  out[idx] = f2bf(src[idx & 32767]);
}

// ---------------------------------------------------------------- kernel 1
// QKVT projection v3: staging now uses float4 global reads (16 loads/thread
// instead of 128 scalar dwords) + in-quad 4x4 shfl transpose, and the staged
// tile row stride is 264 shorts so transposed ds_writes spread banks
// (was an 8-way conflict at stride 256). Values bit-identical.
__global__ __launch_bounds__(512) void k_qkvt(
    const float* __restrict__ ft, const float* __restrict__ fi,
    const short* __restrict__ Wb,
    const float* __restrict__ bq, const float* __restrict__ bk,
    const float* __restrict__ bvp, const float* __restrict__ bt,
    char* __restrict__ Qb8, char* __restrict__ Kb8,
    char* __restrict__ Vb8, short* __restrict__ Tb) {
  __shared__ short lt[64 * XLD];   // 33 KB, swizzled [n][c], stride 264
  __shared__ short li[64 * XLD];

  int tid = threadIdx.x;
  int b = blockIdx.x >> 6, nt = blockIdx.x & 63;
  int n0 = nt * 64;

  // ---- stage both tiles transposed: quad lane j loads float4 (4 n) of row
  //      c = cb*4+j; two-step shfl butterfly -> lane j holds n = nb*4+j,
  //      c = cb*4..+3; pkbf; one b64 write.
  int qd = tid >> 2, j = tid & 3;
#pragma unroll
  for (int t = 0; t < 2; ++t) {
    const float* src = (t == 0 ? ft : fi) + (size_t)b * CIN * NPIX + n0;
    short* dst = (t == 0) ? lt : li;
#pragma unroll
    for (int p = 0; p < 8; ++p) {
      int ti = p * 128 + qd;
      int nb = ti & 15, cb = ti >> 4;          // n-block 0..15, c-block 0..63
      f32x4 x = *(const f32x4*)&src[(size_t)(cb * 4 + j) * NPIX + nb * 4];
      // step 1: swap bit0(lane) <-> bit0(elem)
      float t0 = __shfl_xor(x.y, 1);
      float t1 = __shfl_xor(x.x, 1);
      float t2 = __shfl_xor(x.w, 1);
      float t3 = __shfl_xor(x.z, 1);
      bool od = (j & 1);
      float a0 = od ? t0 : x.x;
      float a1 = od ? x.y : t1;
      float a2 = od ? t2 : x.z;
      float a3 = od ? x.w : t3;
      // step 2: swap bit1(lane) <-> bit1(elem)
      float u0 = __shfl_xor(a0, 2);
      float u1 = __shfl_xor(a1, 2);
      float u2 = __shfl_xor(a2, 2);
      float u3 = __shfl_xor(a3, 2);
      bool hi2 = (j & 2);
      float b0 = hi2 ? u2 : a0;
      float b1 = hi2 ? u3 : a1;
      float b2 = hi2 ? a2 : u0;
      float b3 = hi2 ? a3 : u1;
      int n = nb * 4 + j, c0 = cb * 4;
      union { unsigned u[2]; s16x4 v4; } pv;
      pv.u[0] = pkbf(b0, b1);
      pv.u[1] = pkbf(b2, b3);
      int di = n * XLD + ((((c0 >> 3) ^ (n & 7)) << 3)) + (c0 & 7);
      *(s16x4*)&dst[di] = pv.v4;
    }
  }
  __syncthreads();

  int w = tid >> 6, lane = tid & 63;
  int lr = lane & 15, hg = lane >> 4;
  int op = w >> 1, half = w & 1;

  const short* X = (op == 1 || op == 2) ? li : lt;
  const short* W = Wb + op * (CD * CIN);

  f32x4 acc[4][4] = {};

  if (op != 2) {
#pragma unroll
    for (int ks = 0; ks < 8; ++ks) {
      s16x8 a[4];
#pragma unroll
      for (int ni = 0; ni < 4; ++ni) {
        int row = ni * 16 + lr;
        int di = row * XLD + (((ks * 4 + hg) ^ (row & 7)) << 3);
        a[ni] = *(const s16x8*)&X[di];
      }
#pragma unroll
      for (int cj = 0; cj < 4; ++cj) {
        int cd = half * 64 + cj * 16 + lr;
        s16x8 bfr = *(const s16x8*)&W[cd * CIN + ks * 32 + hg * 8];
#pragma unroll
        for (int ni = 0; ni < 4; ++ni) acc[ni][cj] = MFMA(a[ni], bfr, acc[ni][cj]);
      }
    }
  } else {
#pragma unroll
    for (int ks = 0; ks < 8; ++ks) {
      s16x8 bx[4];
#pragma unroll
      for (int nj = 0; nj < 4; ++nj) {
        int row = nj * 16 + lr;
        int di = row * XLD + (((ks * 4 + hg) ^ (row & 7)) << 3);
        bx[nj] = *(const s16x8*)&X[di];
      }
#pragma unroll
      for (int ci = 0; ci < 4; ++ci) {
        int cd = half * 64 + ci * 16 + lr;
        s16x8 aw = *(const s16x8*)&W[cd * CIN + ks * 32 + hg * 8];
#pragma unroll
        for (int nj = 0; nj < 4; ++nj) acc[ci][nj] = MFMA(aw, bx[nj], acc[ci][nj]);
      }
    }
  }

  // ---- all LDS staging reads complete; reuse lt/li as bounce buffers
  __syncthreads();
  char* QL = (char*)lt;            // 8 KB  [64 rows][128 B]
  char* KL = QL + 8192;            // 8 KB
  char* VL = QL + 16384;           // 8 KB  [128 cd][64 B]
  short* TL = li;                  // 16 KB [64 rows][128 shorts]

  if (op == 0 || op == 1) {
    char* dst = (op == 0) ? QL : KL;
    const float* bias = (op == 0) ? bq : bk;
#pragma unroll
    for (int cj = 0; cj < 4; ++cj) {
      int cd = half * 64 + cj * 16 + lr;
      int dp = (lr >> 3) * 64 + (half * 4 + cj) * 8 + (lr & 7);
      float bb = bias[cd];
#pragma unroll
      for (int ni = 0; ni < 4; ++ni)
#pragma unroll
        for (int r = 0; r < 4; ++r) {
          int rowL = ni * 16 + hg * 4 + r;
          dst[rowL * 128 + dp] = f2fp8(acc[ni][cj][r] + bb);
        }
    }
  } else if (op == 3) {
#pragma unroll
    for (int cj = 0; cj < 4; ++cj) {
      int cd = half * 64 + cj * 16 + lr;
      float bb = bt[cd];
#pragma unroll
      for (int ni = 0; ni < 4; ++ni)
#pragma unroll
        for (int r = 0; r < 4; ++r) {
          int rowL = ni * 16 + hg * 4 + r;
          TL[rowL * 128 + cd] = f2bf(acc[ni][cj][r] + bb);
        }
    }
  } else {  // V
#pragma unroll
    for (int ci = 0; ci < 4; ++ci)
#pragma unroll
      for (int r = 0; r < 4; ++r) {
        int cd = half * 64 + ci * 16 + hg * 4 + r;
        float bb = bvp[cd];
#pragma unroll
        for (int nj = 0; nj < 4; ++nj) {
          int mp = (lr >> 3) * 32 + nj * 8 + (lr & 7);
          VL[cd * 64 + mp] = f2fp8(acc[ci][nj][r] + bb);
        }
      }
  }
  __syncthreads();

  // ---- coalesced readback: dwordx4 stores only
  {
    // Q: 64 rows x 128 B; 8 threads/row x 16 B
    int row = tid >> 3, off = (tid & 7) * 16;
    *(s16x8*)(Qb8 + ((size_t)b * NPIX + n0 + row) * CD + off) =
        *(const s16x8*)(QL + row * 128 + off);
    *(s16x8*)(Kb8 + ((size_t)b * NPIX + n0 + row) * CD + off) =
        *(const s16x8*)(KL + row * 128 + off);
  }
  {
    // V: 128 cd x 64 B; 4 threads/row x 16 B
    int cd = tid >> 2, off = (tid & 3) * 16;
    *(s16x8*)(Vb8 + ((size_t)b * CD + cd) * NPIX + n0 + off) =
        *(const s16x8*)(VL + cd * 64 + off);
  }
  {
    // T: 64 rows x 256 B; 16 threads/row x 16 B, 2 passes
    const char* TLB = (const char*)TL;
#pragma unroll
    for (int p = 0; p < 2; ++p) {
      int row = p * 32 + (tid >> 4), offB = (tid & 15) * 16;
      *(s16x8*)((char*)&Tb[((size_t)b * NPIX + n0 + row) * CD] + offB) =
          *(const s16x8*)(TLB + row * 256 + offB);
    }
  }
}

// ------------------------------------------------ k_attn helpers
// exp2(scale) + row-sum + fp8 repack (one permlane per fragment-pair)
__device__ __forceinline__ void sm8(f32x16& sp, float& li, long (&pb)[2]) {
  const float c2s = 0.12752040381941257f;  // log2(e) / sqrt(128)
#pragma unroll
  for (int r = 0; r < 16; ++r) sp[r] = __builtin_amdgcn_exp2f(sp[r] * c2s);
  float s8[8];
#pragma unroll
  for (int i = 0; i < 8; ++i) s8[i] = sp[i] + sp[i + 8];
#pragma unroll
  for (int i = 0; i < 4; ++i) s8[i] += s8[i + 4];
  float s1 = (s8[0] + s8[1]) + (s8[2] + s8[3]);
  u32x2 sr = __builtin_amdgcn_permlane32_swap(asu(s1), asu(s1), false, false);
  li += asf(sr.x) + asf(sr.y);

  unsigned w0 = (unsigned)__builtin_amdgcn_cvt_pk_fp8_f32(sp[0], sp[1], 0, false);
  w0 = (unsigned)__builtin_amdgcn_cvt_pk_fp8_f32(sp[2], sp[3], (int)w0, true);
  unsigned w1 = (unsigned)__builtin_amdgcn_cvt_pk_fp8_f32(sp[4], sp[5], 0, false);
  w1 = (unsigned)__builtin_amdgcn_cvt_pk_fp8_f32(sp[6], sp[7], (int)w1, true);
  unsigned w2 = (unsigned)__builtin_amdgcn_cvt_pk_fp8_f32(sp[8], sp[9], 0, false);
  w2 = (unsigned)__builtin_amdgcn_cvt_pk_fp8_f32(sp[10], sp[11], (int)w2, true);
  unsigned w3 = (unsigned)__builtin_amdgcn_cvt_pk_fp8_f32(sp[12], sp[13], 0, false);
  w3 = (unsigned)__builtin_amdgcn_cvt_pk_fp8_f32(sp[14], sp[15], (int)w3, true);
  u32x2 rA = __builtin_amdgcn_permlane32_swap(w0, w1, false, false);
  u32x2 rB = __builtin_amdgcn_permlane32_swap(w2, w3, false, false);
  pb[0] = (long)(((unsigned long)rA.y << 32) | rA.x);
  pb[1] = (long)(((unsigned long)rB.y << 32) | rB.x);
}
__device__ __forceinline__ void pub_set(float* buf, float* lmlrow,
                                        const f32x16 (&o)[4], float li,
                                        int row, int h) {
#pragma unroll
  for (int dc = 0; dc < 4; ++dc)
#pragma unroll
    for (int rr = 0; rr < 4; ++rr) {
      int dq = dc * 8 + rr * 2 + h;
      int dqs = dq ^ (row & 15);
      f32x4 v;
      v.x = o[dc][rr * 4 + 0]; v.y = o[dc][rr * 4 + 1];
      v.z = o[dc][rr * 4 + 2]; v.w = o[dc][rr * 4 + 3];
      *(f32x4*)&buf[row * 128 + dqs * 4] = v;
    }
  if (h == 0) lmlrow[row] = li;
}
__device__ __forceinline__ void mrg_set(const float* buf, const float* lmlrow,
                                        f32x16 (&o)[4], float& li,
                                        int row, int h) {
#pragma unroll
  for (int dc = 0; dc < 4; ++dc)
#pragma unroll
    for (int rr = 0; rr < 4; ++rr) {
      int dq = dc * 8 + rr * 2 + h;
      int dqs = dq ^ (row & 15);
      f32x4 v = *(const f32x4*)&buf[row * 128 + dqs * 4];
      o[dc][rr * 4 + 0] += v.x; o[dc][rr * 4 + 1] += v.y;
      o[dc][rr * 4 + 2] += v.z; o[dc][rr * 4 + 3] += v.w;
    }
  li += lmlrow[row];
}
// finalize X = O/li + tproj (bf16) into LDS, K-style 16-granule swizzle
__device__ __forceinline__ void xw_set(short* Xl, const short* __restrict__ Tb,
                                       size_t rowOff, const f32x16 (&o)[4],
                                       float li, int row, int h) {
  float inv = 1.0f / li;
#pragma unroll
  for (int dc = 0; dc < 4; ++dc)
#pragma unroll
    for (int rr = 0; rr < 4; ++rr) {
      int d = dc * 32 + rr * 8 + 4 * h;
      size_t off = rowOff + d;
      s16x4 tp = *(const s16x4*)&Tb[off];
      float f0 = o[dc][rr * 4 + 0] * inv + bf2f(tp.x);
      float f1 = o[dc][rr * 4 + 1] * inv + bf2f(tp.y);
      float f2 = o[dc][rr * 4 + 2] * inv + bf2f(tp.z);
      float f3 = o[dc][rr * 4 + 3] * inv + bf2f(tp.w);
      union { unsigned u[2]; s16x4 v; } xv;
      xv.u[0] = pkbf(f0, f1); xv.u[1] = pkbf(f2, f3);
      int g2 = d >> 3;
      *(s16x4*)&Xl[row * 128 + ((g2 ^ (row & 15)) * 8) + (d & 7)] = xv.v;
    }
}

// ---------------------------------------------------------------- kernel 2
// Flash attention v19 (unchanged — MX K=64 fp8, single-barrier window,
// in-block combine + fused out-GEMM).
__global__ __launch_bounds__(512, 2) void k_attn(
    const char* __restrict__ Qb8, const char* __restrict__ Kb8,
    const char* __restrict__ Vb8, const short* __restrict__ Tb,
    const short* __restrict__ Wfb, const float* __restrict__ bfp,
    float* __restrict__ out) {
  __shared__ short KV[81920];    // 160KB; main loop uses first 80KB
  char* KVB = (char*)KV;

  int tid = threadIdx.x;
  int b = blockIdx.x & 7, qt = blockIdx.x >> 3;   // batch -> XCD L2 affinity
  int q0 = qt * 128;
  int w = tid >> 6, lane = tid & 63;
  int l31 = lane & 31, h = lane >> 5;
  int wg = w & 3, grp = w >> 2;   // grp = KV half
  int gt = tid & 255;             // thread within group
  int GBB = grp * 40960;          // group LDS region (bytes): K 2x8K | V 3x8K
  int mbase = grp * 2048;         // this group's KV half

  // staging coords (v17 layouts)
  int kmo[2], vdo[2];
#pragma unroll
  for (int it = 0; it < 2; ++it) {
    int gs = it * 256 + gt;
    { int R = gs >> 4, g = (gs & 15) ^ (R & 15);
      kmo[it] = (2 * R + (g & 1)) * CD + (g >> 1) * 16; }
    { int R = gs >> 3, g = (gs & 7) ^ (R & 7) ^ ((R & 8) >> 1);
      vdo[it] = (2 * R + (g & 1)) * NPIX + (g >> 1) * 16; }
  }
  int ldsbB = (gt & ~63) * 16;    // wave-uniform byte base

  const char* Kbb = Kb8 + (size_t)b * NPIX * CD;
  const char* Vbb = Vb8 + (size_t)b * CD * NPIX;

  auto STAGE = [&](int m1, int kb, int vb) {
#pragma unroll
    for (int it = 0; it < 2; ++it)
      g2l16b(Kbb + (size_t)m1 * CD + kmo[it], KVB + kb + it * 4096 + ldsbB);
#pragma unroll
    for (int it = 0; it < 2; ++it)
      g2l16b(Vbb + (size_t)m1 + vdo[it], KVB + vb + it * 4096 + ldsbB);
  };

  // loop-invariant read offsets
  int a0k[4], a1k[4];
#pragma unroll
  for (int kp = 0; kp < 4; ++kp) {
    int gd = h * 4 + kp;
    { int m = l31, R = m >> 1, g = gd * 2 + (m & 1);
      a0k[kp] = R * 256 + ((g ^ (R & 15)) << 4); }
    { int m = 32 + l31, R = m >> 1, g = gd * 2 + (m & 1);
      a1k[kp] = R * 256 + ((g ^ (R & 15)) << 4); }
  }
  int pva[2][4];
#pragma unroll
  for (int mp = 0; mp < 2; ++mp)
#pragma unroll
    for (int dc = 0; dc < 4; ++dc) {
      int d = dc * 32 + l31, R = d >> 1, g = (h * 2 + mp) * 2 + (d & 1);
      int gl = g ^ (R & 7) ^ ((R & 8) >> 1);
      pva[mp][dc] = R * 128 + (gl << 4);
    }

  // Q operands (fp8, permuted): two 32B MX operands, loop-invariant
  int q = q0 + wg * 32 + l31;
  const char* qrow8 = Qb8 + ((size_t)b * NPIX + q) * CD;
  i32x8 qA, qB;
  {
    l64x2 q0v = *(const l64x2*)(qrow8 + h * 64);
    l64x2 q1v = *(const l64x2*)(qrow8 + h * 64 + 16);
    l64x2 q2v = *(const l64x2*)(qrow8 + h * 64 + 32);
    l64x2 q3v = *(const l64x2*)(qrow8 + h * 64 + 48);
    qA = mk8(q0v, q1v);
    qB = mk8(q2v, q3v);
  }

  f32x16 o[4] = {};               // O^T: d = dc*32 + (r&3)+8*(r>>2)+4h, q = l31
  float li = 0.0f;
  long pb0[2], pb1[2];            // P of PREVIOUS tile (fp8 frags, loop-carried)

  STAGE(mbase, GBB, GBB + 16384);   // tile 0 -> K0, V0

  for (int mt = 0; mt < 32; ++mt) {
    asm volatile("s_waitcnt vmcnt(0)" ::: "memory");
    __builtin_amdgcn_s_barrier();
    __builtin_amdgcn_sched_barrier(0);

    const char* Kc = KVB + GBB + (mt & 1) * 8192;

    // ---- QK(mt): 2 MX K=64 insts per 32-row half
    f32x16 sp0 = {}, sp1 = {};
    __builtin_amdgcn_s_setprio(1);
    {
      i32x8 k0A = mk8(ld128(Kc + a0k[0]), ld128(Kc + a0k[1]));
      i32x8 k0B = mk8(ld128(Kc + a0k[2]), ld128(Kc + a0k[3]));
      i32x8 k1A = mk8(ld128(Kc + a1k[0]), ld128(Kc + a1k[1]));
      i32x8 k1B = mk8(ld128(Kc + a1k[2]), ld128(Kc + a1k[3]));
      sp0 = MFMAX(k0A, qA, sp0);
      sp0 = MFMAX(k0B, qB, sp0);
      sp1 = MFMAX(k1A, qA, sp1);
      sp1 = MFMAX(k1B, qB, sp1);
    }
    __builtin_amdgcn_s_setprio(0);

    // ---- stage(mt+1)
    if (mt < 31)
      STAGE(mbase + (mt + 1) * 64, GBB + ((mt + 1) & 1) * 8192,
            GBB + 16384 + ((mt + 1) % 3) * 8192);

    // ---- PV(mt-1) (loop-carried fp8 P) || SM(mt): 1 MX inst per dc
    if (mt > 0) {
      const char* Vp = KVB + GBB + 16384 + ((mt - 1) % 3) * 8192;
      i32x8 pB = mk8l(pb0[0], pb0[1], pb1[0], pb1[1]);
      __builtin_amdgcn_s_setprio(1);
#pragma unroll
      for (int dc = 0; dc < 4; ++dc) {
        i32x8 vA = mk8(ld128(Vp + pva[0][dc]), ld128(Vp + pva[1][dc]));
        o[dc] = MFMAX(vA, pB, o[dc]);
      }
      __builtin_amdgcn_s_setprio(0);
    }

    sm8(sp0, li, pb0);
    sm8(sp1, li, pb1);

    asm volatile("s_waitcnt lgkmcnt(0)" ::: "memory");
    __builtin_amdgcn_sched_barrier(0);
  }

  // ---- drain: PV(31) from V buf 31%3 = 1
  {
    const char* Vp = KVB + GBB + 16384 + 8192;
    i32x8 pB = mk8l(pb0[0], pb0[1], pb1[0], pb1[1]);
    __builtin_amdgcn_s_setprio(1);
#pragma unroll
    for (int dc = 0; dc < 4; ++dc) {
      i32x8 vA = mk8(ld128(Vp + pva[0][dc]), ld128(Vp + pva[1][dc]));
      o[dc] = MFMAX(vA, pB, o[dc]);
    }
    __builtin_amdgcn_s_setprio(0);
  }

  // ---- epilogue 1: in-block combine; grp1 materializes X (bf16) into LDS
  float* bufO = (float*)KV;            // 64KB
  float* lml = (float*)&KV[32768];     // 512B
  short* Xl = &KV[36864];              // 64KB X region
  int row = wg * 32 + l31;
  size_t rowOff = ((size_t)b * NPIX + q0 + row) * CD;
  __syncthreads();
  if (grp == 0) pub_set(bufO, lml, o, li, row, h);
  __syncthreads();
  if (grp == 1) {
    mrg_set(bufO, lml, o, li, row, h);
    xw_set(Xl, Tb, rowOff, o, li, row, h);
  }
  __syncthreads();

  // ---- epilogue 2: out = Wf . X + bf for this q-tile (all 8 waves, bf16)
  {
    int oc0 = w * 32;
    f32x16 acc[4] = {};
#pragma unroll
    for (int k8 = 0; k8 < 8; ++k8) {
      s16x8 af = *(const s16x8*)&Wfb[(size_t)(oc0 + l31) * CD + k8 * 16 + h * 8];
#pragma unroll
      for (int nb = 0; nb < 4; ++nb) {
        int rx = nb * 32 + l31;
        int g = k8 * 2 + h;
        s16x8 bx = *(const s16x8*)&Xl[rx * 128 + ((g ^ (rx & 15)) * 8)];
        acc[nb] = MFMA32(af, bx, acc[nb]);
      }
    }
    size_t obase = ((size_t)b * CIN + oc0) * NPIX + q0;
#pragma unroll
    for (int nb = 0; nb < 4; ++nb)
#pragma unroll
      for (int r = 0; r < 16; ++r) {
        int ocr = (r & 3) + 8 * (r >> 2) + 4 * h;
        out[obase + (size_t)ocr * NPIX + nb * 32 + l31] = acc[nb][r] + bfp[oc0 + ocr];
      }
  }
}

// ---------------------------------------------------------------- launch
extern "C" void kernel_launch(void* const* d_in, const int* in_sizes, int n_in,
                              void* d_out, int out_size, void* d_ws, size_t ws_size,
                              hipStream_t stream) {
  const float* ft = (const float*)d_in[0];
  const float* fi = (const float*)d_in[1];
  const float* Wq = (const float*)d_in[2];
  const float* bq = (const float*)d_in[3];
  const float* Wk = (const float*)d_in[4];
  const float* bk = (const float*)d_in[5];
  const float* Wv = (const float*)d_in[6];
  const float* bv = (const float*)d_in[7];
  const float* Wt = (const float*)d_in[8];
  const float* bt = (const float*)d_in[9];
  const float* Wf = (const float*)d_in[10];
  const float* bf = (const float*)d_in[11];
  float* out = (float*)d_out;

  short* wsS = (short*)d_ws;
  char* Qb8 = (char*)wsS;                 // 4.2 MB fp8
  char* Kb8 = (char*)(wsS + 4194304);     // 4.2 MB fp8
  char* Vb8 = (char*)(wsS + 8388608);     // 4.2 MB fp8
  short* Tb = wsS + 12582912;             // 8.4 MB bf16
  short* Wb = wsS + 20971520;             // bf16 weights

  k_wconv<<<640, 256, 0, stream>>>(Wq, Wk, Wv, Wt, Wf, Wb);
  k_qkvt<<<512, 512, 0, stream>>>(ft, fi, Wb, bq, bk, bv, bt, Qb8, Kb8, Vb8, Tb);
  k_attn<<<256, 512, 0, stream>>>(Qb8, Kb8, Vb8, Tb, Wb + 4 * CD * CIN, bf, out);
}

// Round 22
// 96.007 us; speedup vs baseline: 1.0259x; 1.0259x over previous
//
#include <hip/hip_runtime.h>
#include <hip/hip_bf16.h>

#define BATCH 8
#define CIN 256
#define CD 128
#define NPIX 4096  // 64*64

typedef __attribute__((ext_vector_type(2))) float f32x2;
typedef __attribute__((ext_vector_type(4))) float f32x4;
typedef __attribute__((ext_vector_type(16))) float f32x16;
typedef __attribute__((ext_vector_type(8))) short s16x8;
typedef __attribute__((ext_vector_type(4))) short s16x4;
typedef __attribute__((ext_vector_type(2))) unsigned u32x2;
typedef __attribute__((ext_vector_type(2))) long l64x2;
typedef __attribute__((ext_vector_type(8))) int i32x8;

__device__ __forceinline__ short f2bf(float f) {
  union { float f; unsigned u; } v; v.f = f;
  unsigned r = v.u + 0x7fffu + ((v.u >> 16) & 1u);
  return (short)(r >> 16);
}
__device__ __forceinline__ float bf2f(short s) {
  union { unsigned u; float f; } v; v.u = ((unsigned)(unsigned short)s) << 16;
  return v.f;
}
__device__ __forceinline__ float asf(unsigned u) {
  union { unsigned u; float f; } v; v.u = u; return v.f;
}
__device__ __forceinline__ unsigned asu(float f) {
  union { float f; unsigned u; } v; v.f = f; return v.u;
}
// v_cvt_pk_bf16_f32 (T12)
__device__ __forceinline__ unsigned pkbf(float a, float b) {
  unsigned r;
  asm("v_cvt_pk_bf16_f32 %0, %1, %2" : "=v"(r) : "v"(a), "v"(b));
  return r;
}
// scalar f32 -> fp8 e4m3 (OCP), via packed cvt
__device__ __forceinline__ char f2fp8(float v) {
  return (char)((unsigned)__builtin_amdgcn_cvt_pk_fp8_f32(v, v, 0, false) & 0xffu);
}

#define MFMA(a, b, c) __builtin_amdgcn_mfma_f32_16x16x32_bf16((a), (b), (c), 0, 0, 0)
#define MFMA32(a, b, c) __builtin_amdgcn_mfma_f32_32x32x16_bf16((a), (b), (c), 0, 0, 0)
// MX-scaled fp8 K=64, scales = E8M0 127 -> x1.0 exact (2x the K=16 fp8 rate)
#define MFMAX(a, b, c) \
  __builtin_amdgcn_mfma_scale_f32_32x32x64_f8f6f4((a), (b), (c), 0, 0, 0, 127, 0, 127)

// async global->LDS, 16B per lane (char-ptr version)
__device__ __forceinline__ void g2l16b(const char* g, char* l) {
  __builtin_amdgcn_global_load_lds(
      (const __attribute__((address_space(1))) void*)g,
      (__attribute__((address_space(3))) void*)l, 16, 0, 0);
}

// b128 LDS read, viewed as 2x i64
__device__ __forceinline__ l64x2 ld128(const char* p) {
  union { s16x8 v; l64x2 l; } u;
  u.v = *(const s16x8*)p;
  return u.l;
}
// build the 8-VGPR (32B) MX operand from two b128s / four i64s
__device__ __forceinline__ i32x8 mk8(l64x2 a, l64x2 b) {
  union { long l[4]; i32x8 v; } u;
  u.l[0] = a.x; u.l[1] = a.y; u.l[2] = b.x; u.l[3] = b.y;
  return u.v;
}
__device__ __forceinline__ i32x8 mk8l(long a, long b, long c, long d) {
  union { long l[4]; i32x8 v; } u;
  u.l[0] = a; u.l[1] = b; u.l[2] = c; u.l[3] = d;
  return u.v;
}

// ---------------------------------------------------------------- kernel 0
__global__ void k_wconv(const float* __restrict__ Wq, const float* __restrict__ Wk,
                        const float* __restrict__ Wv, const float* __restrict__ Wt,
                        const float* __restrict__ Wf, short* __restrict__ out) {
  int idx = blockIdx.x * 256 + threadIdx.x;  // 0..163839
  int region = idx >> 15;
  const float* src = (region == 0) ? Wq : (region == 1) ? Wk : (region == 2) ? Wv
                     : (region == 3) ? Wt : Wf;
  out[idx] = f2bf(src[idx & 32767]);
}

// ---------------------------------------------------------------- kernel 1
// QKVT projection v2 (round-20 best): compute unchanged; output path bounces
// through LDS so all global stores are coalesced dwordx4.
__global__ __launch_bounds__(512) void k_qkvt(
    const float* __restrict__ ft, const float* __restrict__ fi,
    const short* __restrict__ Wb,
    const float* __restrict__ bq, const float* __restrict__ bk,
    const float* __restrict__ bvp, const float* __restrict__ bt,
    char* __restrict__ Qb8, char* __restrict__ Kb8,
    char* __restrict__ Vb8, short* __restrict__ Tb) {
  __shared__ short lt[64 * 256];
  __shared__ short li[64 * 256];

  int tid = threadIdx.x;
  int b = blockIdx.x >> 6, nt = blockIdx.x & 63;
  int n0 = nt * 64;

#pragma unroll
  for (int t = 0; t < 2; ++t) {
    const float* src = (t == 0 ? ft : fi) + (size_t)b * CIN * NPIX + n0;
    short* dst = (t == 0) ? lt : li;
#pragma unroll
    for (int it = 0; it < 8; ++it) {
      int id = it * 512 + tid;
      int n = id & 63, cg = id >> 6;
      int c0 = cg * 4;
      float x0 = src[(size_t)(c0 + 0) * NPIX + n];
      float x1 = src[(size_t)(c0 + 1) * NPIX + n];
      float x2 = src[(size_t)(c0 + 2) * NPIX + n];
      float x3 = src[(size_t)(c0 + 3) * NPIX + n];
      union { unsigned u[2]; s16x4 v4; } pv;
      pv.u[0] = pkbf(x0, x1);
      pv.u[1] = pkbf(x2, x3);
      int di = n * 256 + ((((c0 >> 3) ^ (n & 7)) << 3)) + (c0 & 7);
      *(s16x4*)&dst[di] = pv.v4;
    }
  }
  __syncthreads();

  int w = tid >> 6, lane = tid & 63;
  int lr = lane & 15, hg = lane >> 4;
  int op = w >> 1, half = w & 1;

  const short* X = (op == 1 || op == 2) ? li : lt;
  const short* W = Wb + op * (CD * CIN);

  f32x4 acc[4][4] = {};

  if (op != 2) {
#pragma unroll
    for (int ks = 0; ks < 8; ++ks) {
      s16x8 a[4];
#pragma unroll
      for (int ni = 0; ni < 4; ++ni) {
        int row = ni * 16 + lr;
        int di = row * 256 + (((ks * 4 + hg) ^ (row & 7)) << 3);
        a[ni] = *(const s16x8*)&X[di];
      }
#pragma unroll
      for (int cj = 0; cj < 4; ++cj) {
        int cd = half * 64 + cj * 16 + lr;
        s16x8 bfr = *(const s16x8*)&W[cd * CIN + ks * 32 + hg * 8];
#pragma unroll
        for (int ni = 0; ni < 4; ++ni) acc[ni][cj] = MFMA(a[ni], bfr, acc[ni][cj]);
      }
    }
  } else {
#pragma unroll
    for (int ks = 0; ks < 8; ++ks) {
      s16x8 bx[4];
#pragma unroll
      for (int nj = 0; nj < 4; ++nj) {
        int row = nj * 16 + lr;
        int di = row * 256 + (((ks * 4 + hg) ^ (row & 7)) << 3);
        bx[nj] = *(const s16x8*)&X[di];
      }
#pragma unroll
      for (int ci = 0; ci < 4; ++ci) {
        int cd = half * 64 + ci * 16 + lr;
        s16x8 aw = *(const s16x8*)&W[cd * CIN + ks * 32 + hg * 8];
#pragma unroll
        for (int nj = 0; nj < 4; ++nj) acc[ci][nj] = MFMA(aw, bx[nj], acc[ci][nj]);
      }
    }
  }

  // ---- all LDS staging reads complete; reuse lt/li as bounce buffers
  __syncthreads();
  char* QL = (char*)lt;            // 8 KB  [64 rows][128 B]
  char* KL = QL + 8192;            // 8 KB
  char* VL = QL + 16384;           // 8 KB  [128 cd][64 B]
  short* TL = li;                  // 16 KB [64 rows][128 shorts]

  if (op == 0 || op == 1) {
    char* dst = (op == 0) ? QL : KL;
    const float* bias = (op == 0) ? bq : bk;
#pragma unroll
    for (int cj = 0; cj < 4; ++cj) {
      int cd = half * 64 + cj * 16 + lr;
      int dp = (lr >> 3) * 64 + (half * 4 + cj) * 8 + (lr & 7);
      float bb = bias[cd];
#pragma unroll
      for (int ni = 0; ni < 4; ++ni)
#pragma unroll
        for (int r = 0; r < 4; ++r) {
          int rowL = ni * 16 + hg * 4 + r;
          dst[rowL * 128 + dp] = f2fp8(acc[ni][cj][r] + bb);
        }
    }
  } else if (op == 3) {
#pragma unroll
    for (int cj = 0; cj < 4; ++cj) {
      int cd = half * 64 + cj * 16 + lr;
      float bb = bt[cd];
#pragma unroll
      for (int ni = 0; ni < 4; ++ni)
#pragma unroll
        for (int r = 0; r < 4; ++r) {
          int rowL = ni * 16 + hg * 4 + r;
          TL[rowL * 128 + cd] = f2bf(acc[ni][cj][r] + bb);
        }
    }
  } else {  // V
#pragma unroll
    for (int ci = 0; ci < 4; ++ci)
#pragma unroll
      for (int r = 0; r < 4; ++r) {
        int cd = half * 64 + ci * 16 + hg * 4 + r;
        float bb = bvp[cd];
#pragma unroll
        for (int nj = 0; nj < 4; ++nj) {
          int mp = (lr >> 3) * 32 + nj * 8 + (lr & 7);
          VL[cd * 64 + mp] = f2fp8(acc[ci][nj][r] + bb);
        }
      }
  }
  __syncthreads();

  // ---- coalesced readback: dwordx4 stores only
  {
    // Q: 64 rows x 128 B; 8 threads/row x 16 B
    int row = tid >> 3, off = (tid & 7) * 16;
    *(s16x8*)(Qb8 + ((size_t)b * NPIX + n0 + row) * CD + off) =
        *(const s16x8*)(QL + row * 128 + off);
    *(s16x8*)(Kb8 + ((size_t)b * NPIX + n0 + row) * CD + off) =
        *(const s16x8*)(KL + row * 128 + off);
  }
  {
    // V: 128 cd x 64 B; 4 threads/row x 16 B
    int cd = tid >> 2, off = (tid & 3) * 16;
    *(s16x8*)(Vb8 + ((size_t)b * CD + cd) * NPIX + n0 + off) =
        *(const s16x8*)(VL + cd * 64 + off);
  }
  {
    // T: 64 rows x 256 B; 16 threads/row x 16 B, 2 passes
    const char* TLB = (const char*)TL;
#pragma unroll
    for (int p = 0; p < 2; ++p) {
      int row = p * 32 + (tid >> 4), offB = (tid & 15) * 16;
      *(s16x8*)((char*)&Tb[((size_t)b * NPIX + n0 + row) * CD] + offB) =
          *(const s16x8*)(TLB + row * 256 + offB);
    }
  }
}

// ------------------------------------------------ k_attn helpers
// exp2(scale) + row-sum + fp8 repack (one permlane per fragment-pair)
__device__ __forceinline__ void sm8(f32x16& sp, float& li, long (&pb)[2]) {
  const float c2s = 0.12752040381941257f;  // log2(e) / sqrt(128)
#pragma unroll
  for (int r = 0; r < 16; ++r) sp[r] = __builtin_amdgcn_exp2f(sp[r] * c2s);
  float s8[8];
#pragma unroll
  for (int i = 0; i < 8; ++i) s8[i] = sp[i] + sp[i + 8];
#pragma unroll
  for (int i = 0; i < 4; ++i) s8[i] += s8[i + 4];
  float s1 = (s8[0] + s8[1]) + (s8[2] + s8[3]);
  u32x2 sr = __builtin_amdgcn_permlane32_swap(asu(s1), asu(s1), false, false);
  li += asf(sr.x) + asf(sr.y);

  unsigned w0 = (unsigned)__builtin_amdgcn_cvt_pk_fp8_f32(sp[0], sp[1], 0, false);
  w0 = (unsigned)__builtin_amdgcn_cvt_pk_fp8_f32(sp[2], sp[3], (int)w0, true);
  unsigned w1 = (unsigned)__builtin_amdgcn_cvt_pk_fp8_f32(sp[4], sp[5], 0, false);
  w1 = (unsigned)__builtin_amdgcn_cvt_pk_fp8_f32(sp[6], sp[7], (int)w1, true);
  unsigned w2 = (unsigned)__builtin_amdgcn_cvt_pk_fp8_f32(sp[8], sp[9], 0, false);
  w2 = (unsigned)__builtin_amdgcn_cvt_pk_fp8_f32(sp[10], sp[11], (int)w2, true);
  unsigned w3 = (unsigned)__builtin_amdgcn_cvt_pk_fp8_f32(sp[12], sp[13], 0, false);
  w3 = (unsigned)__builtin_amdgcn_cvt_pk_fp8_f32(sp[14], sp[15], (int)w3, true);
  u32x2 rA = __builtin_amdgcn_permlane32_swap(w0, w1, false, false);
  u32x2 rB = __builtin_amdgcn_permlane32_swap(w2, w3, false, false);
  pb[0] = (long)(((unsigned long)rA.y << 32) | rA.x);
  pb[1] = (long)(((unsigned long)rB.y << 32) | rB.x);
}
__device__ __forceinline__ void pub_set(float* buf, float* lmlrow,
                                        const f32x16 (&o)[4], float li,
                                        int row, int h) {
#pragma unroll
  for (int dc = 0; dc < 4; ++dc)
#pragma unroll
    for (int rr = 0; rr < 4; ++rr) {
      int dq = dc * 8 + rr * 2 + h;
      int dqs = dq ^ (row & 15);
      f32x4 v;
      v.x = o[dc][rr * 4 + 0]; v.y = o[dc][rr * 4 + 1];
      v.z = o[dc][rr * 4 + 2]; v.w = o[dc][rr * 4 + 3];
      *(f32x4*)&buf[row * 128 + dqs * 4] = v;
    }
  if (h == 0) lmlrow[row] = li;
}
__device__ __forceinline__ void mrg_set(const float* buf, const float* lmlrow,
                                        f32x16 (&o)[4], float& li,
                                        int row, int h) {
#pragma unroll
  for (int dc = 0; dc < 4; ++dc)
#pragma unroll
    for (int rr = 0; rr < 4; ++rr) {
      int dq = dc * 8 + rr * 2 + h;
      int dqs = dq ^ (row & 15);
      f32x4 v = *(const f32x4*)&buf[row * 128 + dqs * 4];
      o[dc][rr * 4 + 0] += v.x; o[dc][rr * 4 + 1] += v.y;
      o[dc][rr * 4 + 2] += v.z; o[dc][rr * 4 + 3] += v.w;
    }
  li += lmlrow[row];
}
// finalize X = O/li + tproj (bf16) into LDS, K-style 16-granule swizzle
__device__ __forceinline__ void xw_set(short* Xl, const short* __restrict__ Tb,
                                       size_t rowOff, const f32x16 (&o)[4],
                                       float li, int row, int h) {
  float inv = 1.0f / li;
#pragma unroll
  for (int dc = 0; dc < 4; ++dc)
#pragma unroll
    for (int rr = 0; rr < 4; ++rr) {
      int d = dc * 32 + rr * 8 + 4 * h;
      size_t off = rowOff + d;
      s16x4 tp = *(const s16x4*)&Tb[off];
      float f0 = o[dc][rr * 4 + 0] * inv + bf2f(tp.x);
      float f1 = o[dc][rr * 4 + 1] * inv + bf2f(tp.y);
      float f2 = o[dc][rr * 4 + 2] * inv + bf2f(tp.z);
      float f3 = o[dc][rr * 4 + 3] * inv + bf2f(tp.w);
      union { unsigned u[2]; s16x4 v; } xv;
      xv.u[0] = pkbf(f0, f1); xv.u[1] = pkbf(f2, f3);
      int g2 = d >> 3;
      *(s16x4*)&Xl[row * 128 + ((g2 ^ (row & 15)) * 8) + (d & 7)] = xv.v;
    }
}

// ---------------------------------------------------------------- kernel 2
// Flash attention v19 (round-19/20 best — MX K=64 fp8, single-barrier window,
// in-block combine + fused out-GEMM).
__global__ __launch_bounds__(512, 2) void k_attn(
    const char* __restrict__ Qb8, const char* __restrict__ Kb8,
    const char* __restrict__ Vb8, const short* __restrict__ Tb,
    const short* __restrict__ Wfb, const float* __restrict__ bfp,
    float* __restrict__ out) {
  __shared__ short KV[81920];    // 160KB; main loop uses first 80KB
  char* KVB = (char*)KV;

  int tid = threadIdx.x;
  int b = blockIdx.x & 7, qt = blockIdx.x >> 3;   // batch -> XCD L2 affinity
  int q0 = qt * 128;
  int w = tid >> 6, lane = tid & 63;
  int l31 = lane & 31, h = lane >> 5;
  int wg = w & 3, grp = w >> 2;   // grp = KV half
  int gt = tid & 255;             // thread within group
  int GBB = grp * 40960;          // group LDS region (bytes): K 2x8K | V 3x8K
  int mbase = grp * 2048;         // this group's KV half

  // staging coords (v17 layouts)
  int kmo[2], vdo[2];
#pragma unroll
  for (int it = 0; it < 2; ++it) {
    int gs = it * 256 + gt;
    { int R = gs >> 4, g = (gs & 15) ^ (R & 15);
      kmo[it] = (2 * R + (g & 1)) * CD + (g >> 1) * 16; }
    { int R = gs >> 3, g = (gs & 7) ^ (R & 7) ^ ((R & 8) >> 1);
      vdo[it] = (2 * R + (g & 1)) * NPIX + (g >> 1) * 16; }
  }
  int ldsbB = (gt & ~63) * 16;    // wave-uniform byte base

  const char* Kbb = Kb8 + (size_t)b * NPIX * CD;
  const char* Vbb = Vb8 + (size_t)b * CD * NPIX;

  auto STAGE = [&](int m1, int kb, int vb) {
#pragma unroll
    for (int it = 0; it < 2; ++it)
      g2l16b(Kbb + (size_t)m1 * CD + kmo[it], KVB + kb + it * 4096 + ldsbB);
#pragma unroll
    for (int it = 0; it < 2; ++it)
      g2l16b(Vbb + (size_t)m1 + vdo[it], KVB + vb + it * 4096 + ldsbB);
  };

  // loop-invariant read offsets
  int a0k[4], a1k[4];
#pragma unroll
  for (int kp = 0; kp < 4; ++kp) {
    int gd = h * 4 + kp;
    { int m = l31, R = m >> 1, g = gd * 2 + (m & 1);
      a0k[kp] = R * 256 + ((g ^ (R & 15)) << 4); }
    { int m = 32 + l31, R = m >> 1, g = gd * 2 + (m & 1);
      a1k[kp] = R * 256 + ((g ^ (R & 15)) << 4); }
  }
  int pva[2][4];
#pragma unroll
  for (int mp = 0; mp < 2; ++mp)
#pragma unroll
    for (int dc = 0; dc < 4; ++dc) {
      int d = dc * 32 + l31, R = d >> 1, g = (h * 2 + mp) * 2 + (d & 1);
      int gl = g ^ (R & 7) ^ ((R & 8) >> 1);
      pva[mp][dc] = R * 128 + (gl << 4);
    }

  // Q operands (fp8, permuted): two 32B MX operands, loop-invariant
  int q = q0 + wg * 32 + l31;
  const char* qrow8 = Qb8 + ((size_t)b * NPIX + q) * CD;
  i32x8 qA, qB;
  {
    l64x2 q0v = *(const l64x2*)(qrow8 + h * 64);
    l64x2 q1v = *(const l64x2*)(qrow8 + h * 64 + 16);
    l64x2 q2v = *(const l64x2*)(qrow8 + h * 64 + 32);
    l64x2 q3v = *(const l64x2*)(qrow8 + h * 64 + 48);
    qA = mk8(q0v, q1v);
    qB = mk8(q2v, q3v);
  }

  f32x16 o[4] = {};               // O^T: d = dc*32 + (r&3)+8*(r>>2)+4h, q = l31
  float li = 0.0f;
  long pb0[2], pb1[2];            // P of PREVIOUS tile (fp8 frags, loop-carried)

  STAGE(mbase, GBB, GBB + 16384);   // tile 0 -> K0, V0

  for (int mt = 0; mt < 32; ++mt) {
    asm volatile("s_waitcnt vmcnt(0)" ::: "memory");
    __builtin_amdgcn_s_barrier();
    __builtin_amdgcn_sched_barrier(0);

    const char* Kc = KVB + GBB + (mt & 1) * 8192;

    // ---- QK(mt): 2 MX K=64 insts per 32-row half
    f32x16 sp0 = {}, sp1 = {};
    __builtin_amdgcn_s_setprio(1);
    {
      i32x8 k0A = mk8(ld128(Kc + a0k[0]), ld128(Kc + a0k[1]));
      i32x8 k0B = mk8(ld128(Kc + a0k[2]), ld128(Kc + a0k[3]));
      i32x8 k1A = mk8(ld128(Kc + a1k[0]), ld128(Kc + a1k[1]));
      i32x8 k1B = mk8(ld128(Kc + a1k[2]), ld128(Kc + a1k[3]));
      sp0 = MFMAX(k0A, qA, sp0);
      sp0 = MFMAX(k0B, qB, sp0);
      sp1 = MFMAX(k1A, qA, sp1);
      sp1 = MFMAX(k1B, qB, sp1);
    }
    __builtin_amdgcn_s_setprio(0);

    // ---- stage(mt+1)
    if (mt < 31)
      STAGE(mbase + (mt + 1) * 64, GBB + ((mt + 1) & 1) * 8192,
            GBB + 16384 + ((mt + 1) % 3) * 8192);

    // ---- PV(mt-1) (loop-carried fp8 P) || SM(mt): 1 MX inst per dc
    if (mt > 0) {
      const char* Vp = KVB + GBB + 16384 + ((mt - 1) % 3) * 8192;
      i32x8 pB = mk8l(pb0[0], pb0[1], pb1[0], pb1[1]);
      __builtin_amdgcn_s_setprio(1);
#pragma unroll
      for (int dc = 0; dc < 4; ++dc) {
        i32x8 vA = mk8(ld128(Vp + pva[0][dc]), ld128(Vp + pva[1][dc]));
        o[dc] = MFMAX(vA, pB, o[dc]);
      }
      __builtin_amdgcn_s_setprio(0);
    }

    sm8(sp0, li, pb0);
    sm8(sp1, li, pb1);

    asm volatile("s_waitcnt lgkmcnt(0)" ::: "memory");
    __builtin_amdgcn_sched_barrier(0);
  }

  // ---- drain: PV(31) from V buf 31%3 = 1
  {
    const char* Vp = KVB + GBB + 16384 + 8192;
    i32x8 pB = mk8l(pb0[0], pb0[1], pb1[0], pb1[1]);
    __builtin_amdgcn_s_setprio(1);
#pragma unroll
    for (int dc = 0; dc < 4; ++dc) {
      i32x8 vA = mk8(ld128(Vp + pva[0][dc]), ld128(Vp + pva[1][dc]));
      o[dc] = MFMAX(vA, pB, o[dc]);
    }
    __builtin_amdgcn_s_setprio(0);
  }

  // ---- epilogue 1: in-block combine; grp1 materializes X (bf16) into LDS
  float* bufO = (float*)KV;            // 64KB
  float* lml = (float*)&KV[32768];     // 512B
  short* Xl = &KV[36864];              // 64KB X region
  int row = wg * 32 + l31;
  size_t rowOff = ((size_t)b * NPIX + q0 + row) * CD;
  __syncthreads();
  if (grp == 0) pub_set(bufO, lml, o, li, row, h);
  __syncthreads();
  if (grp == 1) {
    mrg_set(bufO, lml, o, li, row, h);
    xw_set(Xl, Tb, rowOff, o, li, row, h);
  }
  __syncthreads();

  // ---- epilogue 2: out = Wf . X + bf for this q-tile (all 8 waves, bf16)
  {
    int oc0 = w * 32;
    f32x16 acc[4] = {};
#pragma unroll
    for (int k8 = 0; k8 < 8; ++k8) {
      s16x8 af = *(const s16x8*)&Wfb[(size_t)(oc0 + l31) * CD + k8 * 16 + h * 8];
#pragma unroll
      for (int nb = 0; nb < 4; ++nb) {
        int rx = nb * 32 + l31;
        int g = k8 * 2 + h;
        s16x8 bx = *(const s16x8*)&Xl[rx * 128 + ((g ^ (rx & 15)) * 8)];
        acc[nb] = MFMA32(af, bx, acc[nb]);
      }
    }
    size_t obase = ((size_t)b * CIN + oc0) * NPIX + q0;
#pragma unroll
    for (int nb = 0; nb < 4; ++nb)
#pragma unroll
      for (int r = 0; r < 16; ++r) {
        int ocr = (r & 3) + 8 * (r >> 2) + 4 * h;
        out[obase + (size_t)ocr * NPIX + nb * 32 + l31] = acc[nb][r] + bfp[oc0 + ocr];
      }
  }
}

// ---------------------------------------------------------------- launch
extern "C" void kernel_launch(void* const* d_in, const int* in_sizes, int n_in,
                              void* d_out, int out_size, void* d_ws, size_t ws_size,
                              hipStream_t stream) {
  const float* ft = (const float*)d_in[0];
  const float* fi = (const float*)d_in[1];
  const float* Wq = (const float*)d_in[2];
  const float* bq = (const float*)d_in[3];
  const float* Wk = (const float*)d_in[4];
  const float* bk = (const float*)d_in[5];
  const float* Wv = (const float*)d_in[6];
  const float* bv = (const float*)d_in[7];
  const float* Wt = (const float*)d_in[8];
  const float* bt = (const float*)d_in[9];
  const float* Wf = (const float*)d_in[10];
  const float* bf = (const float*)d_in[11];
  float* out = (float*)d_out;

  short* wsS = (short*)d_ws;
  char* Qb8 = (char*)wsS;                 // 4.2 MB fp8
  char* Kb8 = (char*)(wsS + 4194304);     // 4.2 MB fp8
  char* Vb8 = (char*)(wsS + 8388608);     // 4.2 MB fp8
  short* Tb = wsS + 12582912;             // 8.4 MB bf16
  short* Wb = wsS + 20971520;             // bf16 weights

  k_wconv<<<640, 256, 0, stream>>>(Wq, Wk, Wv, Wt, Wf, Wb);
  k_qkvt<<<512, 512, 0, stream>>>(ft, fi, Wb, bq, bk, bv, bt, Qb8, Kb8, Vb8, Tb);
  k_attn<<<256, 512, 0, stream>>>(Qb8, Kb8, Vb8, Tb, Wb + 4 * CD * CIN, bf, out);
}